// Round 1
// baseline (1470.796 us; speedup 1.0000x reference)
//
#include <hip/hip_runtime.h>
#include <hip/hip_bf16.h>

#define D 64

__device__ __forceinline__ float sspf(float x) {
    // softplus(x) - log(2), numerically stable
    return fmaxf(x, 0.f) + __logf(1.f + __expf(-fabsf(x))) - 0.6931471805599453f;
}

// h = node_feats @ Wn + bn   (wave-per-row, Wn column in registers)
__global__ __launch_bounds__(256)
void node_proj(const float* __restrict__ nf, const float* __restrict__ Wn,
               const float* __restrict__ bn, float* __restrict__ h, int V_) {
    const int lane = threadIdx.x & 63;
    const int w    = threadIdx.x >> 6;
    const int nw   = blockDim.x >> 6;
    const int gw   = blockIdx.x * nw + w;
    const int gstride = gridDim.x * nw;

    float wr[D];
#pragma unroll
    for (int k = 0; k < D; ++k) wr[k] = Wn[k * D + lane];
    const float br = bn[lane];

    __shared__ float stage[4][D];

    const int trips = (V_ + gstride - 1) / gstride;
    for (int t = 0; t < trips; ++t) {
        const int row = gw + t * gstride;
        const int r   = min(row, V_ - 1);
        stage[w][lane] = nf[(size_t)r * D + lane];
        __syncthreads();
        float acc = br;
#pragma unroll
        for (int k = 0; k < D; ++k) acc = fmaf(stage[w][k], wr[k], acc);
        __syncthreads();
        if (row < V_) h[(size_t)row * D + lane] = acc;
    }
}

// per edge: f = ssp(ssp(e@W1+b1)@W2+b2); msg = h[src]*f; atomic agg[dst] += msg
__global__ __launch_bounds__(256)
void edge_kernel(const float* __restrict__ ef, const float* __restrict__ h,
                 const int* __restrict__ src, const int* __restrict__ dst,
                 const float* __restrict__ W1, const float* __restrict__ b1,
                 const float* __restrict__ W2, const float* __restrict__ b2,
                 float* __restrict__ agg, int E_) {
    const int lane = threadIdx.x & 63;
    const int w    = threadIdx.x >> 6;
    const int nw   = blockDim.x >> 6;
    const int gw   = blockIdx.x * nw + w;
    const int gstride = gridDim.x * nw;

    float w1r[D], w2r[D];
#pragma unroll
    for (int k = 0; k < D; ++k) w1r[k] = W1[k * D + lane];
#pragma unroll
    for (int k = 0; k < D; ++k) w2r[k] = W2[k * D + lane];
    const float b1r = b1[lane];
    const float b2r = b2[lane];

    __shared__ float se[4][D];
    __shared__ float sf[4][D];

    const int trips = (E_ + gstride - 1) / gstride;
    for (int t = 0; t < trips; ++t) {
        const int e  = gw + t * gstride;
        const int ec = min(e, E_ - 1);
        const int s_ = src[ec];
        const int d_ = dst[ec];
        const float hv = h[(size_t)s_ * D + lane];   // gathered, L3-resident
        se[w][lane] = ef[(size_t)ec * D + lane];
        __syncthreads();
        float acc = b1r;
#pragma unroll
        for (int k = 0; k < D; ++k) acc = fmaf(se[w][k], w1r[k], acc);
        sf[w][lane] = sspf(acc);
        __syncthreads();
        float acc2 = b2r;
#pragma unroll
        for (int k = 0; k < D; ++k) acc2 = fmaf(sf[w][k], w2r[k], acc2);
        const float msg = sspf(acc2) * hv;
        if (e < E_) atomicAdd(&agg[(size_t)d_ * D + lane], msg);
    }
}

// out = ssp(agg @ Wc + bc) @ Wo + bo
__global__ __launch_bounds__(256)
void out_proj(const float* __restrict__ agg, const float* __restrict__ Wc,
              const float* __restrict__ bc, const float* __restrict__ Wo,
              const float* __restrict__ bo, float* __restrict__ out, int V_) {
    const int lane = threadIdx.x & 63;
    const int w    = threadIdx.x >> 6;
    const int nw   = blockDim.x >> 6;
    const int gw   = blockIdx.x * nw + w;
    const int gstride = gridDim.x * nw;

    float wcr[D], wor[D];
#pragma unroll
    for (int k = 0; k < D; ++k) wcr[k] = Wc[k * D + lane];
#pragma unroll
    for (int k = 0; k < D; ++k) wor[k] = Wo[k * D + lane];
    const float bcr = bc[lane];
    const float bor = bo[lane];

    __shared__ float sa[4][D];
    __shared__ float st[4][D];

    const int trips = (V_ + gstride - 1) / gstride;
    for (int t = 0; t < trips; ++t) {
        const int row = gw + t * gstride;
        const int r   = min(row, V_ - 1);
        sa[w][lane] = agg[(size_t)r * D + lane];
        __syncthreads();
        float acc = bcr;
#pragma unroll
        for (int k = 0; k < D; ++k) acc = fmaf(sa[w][k], wcr[k], acc);
        st[w][lane] = sspf(acc);
        __syncthreads();
        float acc2 = bor;
#pragma unroll
        for (int k = 0; k < D; ++k) acc2 = fmaf(st[w][k], wor[k], acc2);
        if (row < V_) out[(size_t)row * D + lane] = acc2;
    }
}

extern "C" void kernel_launch(void* const* d_in, const int* in_sizes, int n_in,
                              void* d_out, int out_size, void* d_ws, size_t ws_size,
                              hipStream_t stream) {
    const float* node_feats = (const float*)d_in[0];
    const float* edge_feats = (const float*)d_in[1];
    const int*   src        = (const int*)d_in[2];
    const int*   dst        = (const int*)d_in[3];
    const float* We1        = (const float*)d_in[4];
    const float* be1        = (const float*)d_in[5];
    const float* We2        = (const float*)d_in[6];
    const float* be2        = (const float*)d_in[7];
    const float* Wn         = (const float*)d_in[8];
    const float* bn         = (const float*)d_in[9];
    const float* Wc         = (const float*)d_in[10];
    const float* bc         = (const float*)d_in[11];
    const float* Wo         = (const float*)d_in[12];
    const float* bo         = (const float*)d_in[13];
    float* out = (float*)d_out;

    const int V_ = in_sizes[0] / D;   // 50000
    const int E_ = in_sizes[2];       // 1250000

    float* h   = (float*)d_ws;
    float* agg = h + (size_t)V_ * D;

    hipMemsetAsync(agg, 0, (size_t)V_ * D * sizeof(float), stream);
    node_proj<<<512, 256, 0, stream>>>(node_feats, Wn, bn, h, V_);
    edge_kernel<<<4096, 256, 0, stream>>>(edge_feats, h, src, dst,
                                          We1, be1, We2, be2, agg, E_);
    out_proj<<<512, 256, 0, stream>>>(agg, Wc, bc, Wo, bo, out, V_);
}

// Round 2
// 1168.690 us; speedup vs baseline: 1.2585x; 1.2585x over previous
//
#include <hip/hip_runtime.h>
#include <hip/hip_bf16.h>

#define D 64

__device__ __forceinline__ float sspf(float x) {
    // softplus(x) - log(2), numerically stable
    return fmaxf(x, 0.f) + __logf(1.f + __expf(-fabsf(x))) - 0.6931471805599453f;
}

// broadcast lane k's value to all lanes via v_readlane (VALU pipe, no LDS)
__device__ __forceinline__ float rlane(float v, int k) {
    return __uint_as_float(__builtin_amdgcn_readlane(__float_as_uint(v), (unsigned)k));
}

// h = node_feats @ Wn + bn   (wave-per-row, Wn column in registers, readlane broadcast)
__global__ __launch_bounds__(256)
void node_proj(const float* __restrict__ nf, const float* __restrict__ Wn,
               const float* __restrict__ bn, float* __restrict__ h, int V_) {
    const int lane = threadIdx.x & 63;
    const int w    = threadIdx.x >> 6;
    const int nw   = blockDim.x >> 6;
    const int gw   = blockIdx.x * nw + w;
    const int gstride = gridDim.x * nw;

    float wr[D];
#pragma unroll
    for (int k = 0; k < D; ++k) wr[k] = Wn[k * D + lane];
    const float br = bn[lane];

    for (int row = gw; row < V_; row += gstride) {
        const float x = nf[(size_t)row * D + lane];
        float p0 = br, p1 = 0.f, p2 = 0.f, p3 = 0.f;
#pragma unroll
        for (int k = 0; k < D; k += 4) {
            p0 = fmaf(rlane(x, k + 0), wr[k + 0], p0);
            p1 = fmaf(rlane(x, k + 1), wr[k + 1], p1);
            p2 = fmaf(rlane(x, k + 2), wr[k + 2], p2);
            p3 = fmaf(rlane(x, k + 3), wr[k + 3], p3);
        }
        h[(size_t)row * D + lane] = (p0 + p1) + (p2 + p3);
    }
}

// per edge: f = ssp(ssp(e@W1+b1)@W2+b2); msg = h[src]*f; atomic agg[dst] += msg
// wave-per-edge, weights in VGPRs, readlane broadcasts, barrier-free,
// software-pipelined global loads.
__global__ __launch_bounds__(256)
void edge_kernel(const float* __restrict__ ef, const float* __restrict__ h,
                 const int* __restrict__ src, const int* __restrict__ dst,
                 const float* __restrict__ W1, const float* __restrict__ b1,
                 const float* __restrict__ W2, const float* __restrict__ b2,
                 float* __restrict__ agg, int E_) {
    const int lane = threadIdx.x & 63;
    const int w    = threadIdx.x >> 6;
    const int nw   = blockDim.x >> 6;
    const int gw   = blockIdx.x * nw + w;
    const int gstride = gridDim.x * nw;

    float w1r[D], w2r[D];
#pragma unroll
    for (int k = 0; k < D; ++k) w1r[k] = W1[k * D + lane];
#pragma unroll
    for (int k = 0; k < D; ++k) w2r[k] = W2[k * D + lane];
    const float b1r = b1[lane];
    const float b2r = b2[lane];

    int e = gw;
    if (e >= E_) return;

    // prologue loads
    int   d_ = dst[e];
    float ev = ef[(size_t)e * D + lane];
    float hv = h[(size_t)src[e] * D + lane];

    while (true) {
        // issue next trip's loads early (in flight across this trip's compute)
        const int en = e + gstride;
        int dn = 0; float evn = 0.f, hvn = 0.f;
        if (en < E_) {
            dn  = dst[en];
            evn = ef[(size_t)en * D + lane];
            hvn = h[(size_t)src[en] * D + lane];
        }

        // layer 1: acc[lane] = sum_k ev_k * W1[k][lane]
        float p0 = b1r, p1 = 0.f, p2 = 0.f, p3 = 0.f;
#pragma unroll
        for (int k = 0; k < D; k += 4) {
            p0 = fmaf(rlane(ev, k + 0), w1r[k + 0], p0);
            p1 = fmaf(rlane(ev, k + 1), w1r[k + 1], p1);
            p2 = fmaf(rlane(ev, k + 2), w1r[k + 2], p2);
            p3 = fmaf(rlane(ev, k + 3), w1r[k + 3], p3);
        }
        const float fv = sspf((p0 + p1) + (p2 + p3));

        // layer 2
        float q0 = b2r, q1 = 0.f, q2 = 0.f, q3 = 0.f;
#pragma unroll
        for (int k = 0; k < D; k += 4) {
            q0 = fmaf(rlane(fv, k + 0), w2r[k + 0], q0);
            q1 = fmaf(rlane(fv, k + 1), w2r[k + 1], q1);
            q2 = fmaf(rlane(fv, k + 2), w2r[k + 2], q2);
            q3 = fmaf(rlane(fv, k + 3), w2r[k + 3], q3);
        }
        const float msg = sspf((q0 + q1) + (q2 + q3)) * hv;

        atomicAdd(&agg[(size_t)d_ * D + lane], msg);

        if (en >= E_) break;
        e = en; d_ = dn; ev = evn; hv = hvn;
    }
}

// out = ssp(agg @ Wc + bc) @ Wo + bo   (wave-per-row, readlane broadcasts)
__global__ __launch_bounds__(256)
void out_proj(const float* __restrict__ agg, const float* __restrict__ Wc,
              const float* __restrict__ bc, const float* __restrict__ Wo,
              const float* __restrict__ bo, float* __restrict__ out, int V_) {
    const int lane = threadIdx.x & 63;
    const int w    = threadIdx.x >> 6;
    const int nw   = blockDim.x >> 6;
    const int gw   = blockIdx.x * nw + w;
    const int gstride = gridDim.x * nw;

    float wcr[D], wor[D];
#pragma unroll
    for (int k = 0; k < D; ++k) wcr[k] = Wc[k * D + lane];
#pragma unroll
    for (int k = 0; k < D; ++k) wor[k] = Wo[k * D + lane];
    const float bcr = bc[lane];
    const float bor = bo[lane];

    for (int row = gw; row < V_; row += gstride) {
        const float x = agg[(size_t)row * D + lane];
        float p0 = bcr, p1 = 0.f, p2 = 0.f, p3 = 0.f;
#pragma unroll
        for (int k = 0; k < D; k += 4) {
            p0 = fmaf(rlane(x, k + 0), wcr[k + 0], p0);
            p1 = fmaf(rlane(x, k + 1), wcr[k + 1], p1);
            p2 = fmaf(rlane(x, k + 2), wcr[k + 2], p2);
            p3 = fmaf(rlane(x, k + 3), wcr[k + 3], p3);
        }
        const float tv = sspf((p0 + p1) + (p2 + p3));

        float q0 = bor, q1 = 0.f, q2 = 0.f, q3 = 0.f;
#pragma unroll
        for (int k = 0; k < D; k += 4) {
            q0 = fmaf(rlane(tv, k + 0), wor[k + 0], q0);
            q1 = fmaf(rlane(tv, k + 1), wor[k + 1], q1);
            q2 = fmaf(rlane(tv, k + 2), wor[k + 2], q2);
            q3 = fmaf(rlane(tv, k + 3), wor[k + 3], q3);
        }
        out[(size_t)row * D + lane] = (q0 + q1) + (q2 + q3);
    }
}

extern "C" void kernel_launch(void* const* d_in, const int* in_sizes, int n_in,
                              void* d_out, int out_size, void* d_ws, size_t ws_size,
                              hipStream_t stream) {
    const float* node_feats = (const float*)d_in[0];
    const float* edge_feats = (const float*)d_in[1];
    const int*   src        = (const int*)d_in[2];
    const int*   dst        = (const int*)d_in[3];
    const float* We1        = (const float*)d_in[4];
    const float* be1        = (const float*)d_in[5];
    const float* We2        = (const float*)d_in[6];
    const float* be2        = (const float*)d_in[7];
    const float* Wn         = (const float*)d_in[8];
    const float* bn         = (const float*)d_in[9];
    const float* Wc         = (const float*)d_in[10];
    const float* bc         = (const float*)d_in[11];
    const float* Wo         = (const float*)d_in[12];
    const float* bo         = (const float*)d_in[13];
    float* out = (float*)d_out;

    const int V_ = in_sizes[0] / D;   // 50000
    const int E_ = in_sizes[2];       // 1250000

    float* h   = (float*)d_ws;
    float* agg = h + (size_t)V_ * D;

    hipMemsetAsync(agg, 0, (size_t)V_ * D * sizeof(float), stream);
    node_proj<<<1024, 256, 0, stream>>>(node_feats, Wn, bn, h, V_);
    edge_kernel<<<4096, 256, 0, stream>>>(edge_feats, h, src, dst,
                                          We1, be1, We2, be2, agg, E_);
    out_proj<<<1024, 256, 0, stream>>>(agg, Wc, bc, Wo, bo, out, V_);
}

// Round 3
// 716.292 us; speedup vs baseline: 2.0533x; 1.6316x over previous
//
#include <hip/hip_runtime.h>
#include <hip/hip_bf16.h>

#define D 64
#define STRIDE 72   // shorts per LDS row: 64 + 8 pad; 144 B keeps 16B alignment for ds_read_b128

typedef __attribute__((ext_vector_type(8))) short bf16x8;
typedef __attribute__((ext_vector_type(4))) float f32x4;
typedef __attribute__((ext_vector_type(4))) short short4v;

__device__ __forceinline__ float sspf(float x) {
    // softplus(x) - log(2), numerically stable
    return fmaxf(x, 0.f) + __logf(1.f + __expf(-fabsf(x))) - 0.6931471805599453f;
}

// float -> bf16 bits, round-to-nearest-even (finite inputs)
__device__ __forceinline__ unsigned short f2bf(float x) {
    union { float f; unsigned u; } v; v.f = x;
    unsigned r = v.u + 0x7fff + ((v.u >> 16) & 1);
    return (unsigned short)(r >> 16);
}

__device__ __forceinline__ float rlane(float v, int k) {
    return __uint_as_float(__builtin_amdgcn_readlane(__float_as_uint(v), (unsigned)k));
}

// h = node_feats @ Wn + bn   (fp32, wave-per-row readlane; small: V=50k)
__global__ __launch_bounds__(256)
void node_proj(const float* __restrict__ nf, const float* __restrict__ Wn,
               const float* __restrict__ bn, float* __restrict__ h, int V_) {
    const int lane = threadIdx.x & 63;
    const int w    = threadIdx.x >> 6;
    const int nw   = blockDim.x >> 6;
    const int gw   = blockIdx.x * nw + w;
    const int gstride = gridDim.x * nw;

    float wr[D];
#pragma unroll
    for (int k = 0; k < D; ++k) wr[k] = Wn[k * D + lane];
    const float br = bn[lane];

    for (int row = gw; row < V_; row += gstride) {
        const float x = nf[(size_t)row * D + lane];
        float p0 = br, p1 = 0.f, p2 = 0.f, p3 = 0.f;
#pragma unroll
        for (int k = 0; k < D; k += 4) {
            p0 = fmaf(rlane(x, k + 0), wr[k + 0], p0);
            p1 = fmaf(rlane(x, k + 1), wr[k + 1], p1);
            p2 = fmaf(rlane(x, k + 2), wr[k + 2], p2);
            p3 = fmaf(rlane(x, k + 3), wr[k + 3], p3);
        }
        h[(size_t)row * D + lane] = (p0 + p1) + (p2 + p3);
    }
}

// MFMA edge kernel: per wave-private 16-edge tile
//   f = ssp(ssp(E16 @ W1 + b1) @ W2 + b2); msg = h[src]*f; atomic agg[dst] += msg
// A-layout (16x16x32): A[m=lane&15][k=(lane>>4)*8+j]; C/D: col=lane&15, row=(lane>>4)*4+reg
__global__ __launch_bounds__(256)
void edge_mfma(const float* __restrict__ ef, const float* __restrict__ h,
               const int* __restrict__ src, const int* __restrict__ dst,
               const float* __restrict__ W1, const float* __restrict__ b1,
               const float* __restrict__ W2, const float* __restrict__ b2,
               float* __restrict__ agg, int E_) {
    const int lane = threadIdx.x & 63;
    const int w    = threadIdx.x >> 6;
    const int q    = lane >> 4;
    const int c    = lane & 15;

    __shared__ short sbuf[4][16 * STRIDE];   // wave-private staging (no cross-wave sharing)
    short* buf = sbuf[w];

    // persistent weight B-fragments: B[k=s*32+q*8+j][n=t*16+c]
    bf16x8 wf1[2][4], wf2[2][4];
    float b1v[4], b2v[4];
#pragma unroll
    for (int s = 0; s < 2; ++s)
#pragma unroll
        for (int t = 0; t < 4; ++t)
#pragma unroll
            for (int j = 0; j < 8; ++j) {
                wf1[s][t][j] = (short)f2bf(W1[(s * 32 + q * 8 + j) * D + t * 16 + c]);
                wf2[s][t][j] = (short)f2bf(W2[(s * 32 + q * 8 + j) * D + t * 16 + c]);
            }
#pragma unroll
    for (int t = 0; t < 4; ++t) { b1v[t] = b1[t * 16 + c]; b2v[t] = b2[t * 16 + c]; }

    const int ntiles = E_ >> 4;   // E = 1,250,000 = 78125 * 16 exactly
    const int wid = blockIdx.x * (blockDim.x >> 6) + w;
    const int nwv = gridDim.x * (blockDim.x >> 6);
    const float4* ef4 = (const float4*)ef;

    for (int tile = wid; tile < ntiles; tile += nwv) {
        const int base = tile << 4;

        // ---- stage 16 edge rows fp32 -> bf16 LDS (coalesced float4, ds_write_b64) ----
#pragma unroll
        for (int i = 0; i < 4; ++i) {
            const int fl = i * 64 + lane;                 // float4 index within tile
            const float4 v = ef4[(size_t)base * 16 + fl];
            short4v s4;
            s4[0] = (short)f2bf(v.x); s4[1] = (short)f2bf(v.y);
            s4[2] = (short)f2bf(v.z); s4[3] = (short)f2bf(v.w);
            const int e = fl >> 4, d4 = fl & 15;
            *(short4v*)&buf[e * STRIDE + d4 * 4] = s4;
        }
        __builtin_amdgcn_wave_barrier();

        // ---- layer 1: A = edge rows, B = W1 frags ----
        const bf16x8 a0 = *(const bf16x8*)&buf[c * STRIDE + 0 * 32 + q * 8];
        const bf16x8 a1 = *(const bf16x8*)&buf[c * STRIDE + 1 * 32 + q * 8];
        __builtin_amdgcn_wave_barrier();

        f32x4 acc[4];
#pragma unroll
        for (int t = 0; t < 4; ++t) {
            f32x4 z = {0.f, 0.f, 0.f, 0.f};
            z = __builtin_amdgcn_mfma_f32_16x16x32_bf16(a0, wf1[0][t], z, 0, 0, 0);
            z = __builtin_amdgcn_mfma_f32_16x16x32_bf16(a1, wf1[1][t], z, 0, 0, 0);
            acc[t] = z;
        }

        // ---- ssp, write f back to LDS (C-layout -> row-major bf16) ----
#pragma unroll
        for (int t = 0; t < 4; ++t)
#pragma unroll
            for (int r = 0; r < 4; ++r) {
                const float fv = sspf(acc[t][r] + b1v[t]);
                buf[(q * 4 + r) * STRIDE + t * 16 + c] = (short)f2bf(fv);
            }
        __builtin_amdgcn_wave_barrier();

        // ---- layer 2: A = f rows, B = W2 frags ----
        const bf16x8 p0 = *(const bf16x8*)&buf[c * STRIDE + 0 * 32 + q * 8];
        const bf16x8 p1 = *(const bf16x8*)&buf[c * STRIDE + 1 * 32 + q * 8];
        __builtin_amdgcn_wave_barrier();
#pragma unroll
        for (int t = 0; t < 4; ++t) {
            f32x4 z = {0.f, 0.f, 0.f, 0.f};
            z = __builtin_amdgcn_mfma_f32_16x16x32_bf16(p0, wf2[0][t], z, 0, 0, 0);
            z = __builtin_amdgcn_mfma_f32_16x16x32_bf16(p1, wf2[1][t], z, 0, 0, 0);
            acc[t] = z;
        }

        // ---- epilogue: gather h[src] (fp32), modulate, atomic scatter ----
        int sidx[4], didx[4];
#pragma unroll
        for (int r = 0; r < 4; ++r) {
            sidx[r] = src[base + q * 4 + r];
            didx[r] = dst[base + q * 4 + r];
        }
#pragma unroll
        for (int t = 0; t < 4; ++t)
#pragma unroll
            for (int r = 0; r < 4; ++r) {
                const float hv  = h[(size_t)sidx[r] * D + t * 16 + c];
                const float msg = sspf(acc[t][r] + b2v[t]) * hv;
                atomicAdd(&agg[(size_t)didx[r] * D + t * 16 + c], msg);
            }
    }
}

// out = ssp(agg @ Wc + bc) @ Wo + bo   (fp32, wave-per-row readlane; small: V=50k)
__global__ __launch_bounds__(256)
void out_proj(const float* __restrict__ agg, const float* __restrict__ Wc,
              const float* __restrict__ bc, const float* __restrict__ Wo,
              const float* __restrict__ bo, float* __restrict__ out, int V_) {
    const int lane = threadIdx.x & 63;
    const int w    = threadIdx.x >> 6;
    const int nw   = blockDim.x >> 6;
    const int gw   = blockIdx.x * nw + w;
    const int gstride = gridDim.x * nw;

    float wcr[D], wor[D];
#pragma unroll
    for (int k = 0; k < D; ++k) wcr[k] = Wc[k * D + lane];
#pragma unroll
    for (int k = 0; k < D; ++k) wor[k] = Wo[k * D + lane];
    const float bcr = bc[lane];
    const float bor = bo[lane];

    for (int row = gw; row < V_; row += gstride) {
        const float x = agg[(size_t)row * D + lane];
        float p0 = bcr, p1 = 0.f, p2 = 0.f, p3 = 0.f;
#pragma unroll
        for (int k = 0; k < D; k += 4) {
            p0 = fmaf(rlane(x, k + 0), wcr[k + 0], p0);
            p1 = fmaf(rlane(x, k + 1), wcr[k + 1], p1);
            p2 = fmaf(rlane(x, k + 2), wcr[k + 2], p2);
            p3 = fmaf(rlane(x, k + 3), wcr[k + 3], p3);
        }
        const float tv = sspf((p0 + p1) + (p2 + p3));

        float q0 = bor, q1 = 0.f, q2 = 0.f, q3 = 0.f;
#pragma unroll
        for (int k = 0; k < D; k += 4) {
            q0 = fmaf(rlane(tv, k + 0), wor[k + 0], q0);
            q1 = fmaf(rlane(tv, k + 1), wor[k + 1], q1);
            q2 = fmaf(rlane(tv, k + 2), wor[k + 2], q2);
            q3 = fmaf(rlane(tv, k + 3), wor[k + 3], q3);
        }
        out[(size_t)row * D + lane] = (q0 + q1) + (q2 + q3);
    }
}

extern "C" void kernel_launch(void* const* d_in, const int* in_sizes, int n_in,
                              void* d_out, int out_size, void* d_ws, size_t ws_size,
                              hipStream_t stream) {
    const float* node_feats = (const float*)d_in[0];
    const float* edge_feats = (const float*)d_in[1];
    const int*   src        = (const int*)d_in[2];
    const int*   dst        = (const int*)d_in[3];
    const float* We1        = (const float*)d_in[4];
    const float* be1        = (const float*)d_in[5];
    const float* We2        = (const float*)d_in[6];
    const float* be2        = (const float*)d_in[7];
    const float* Wn         = (const float*)d_in[8];
    const float* bn         = (const float*)d_in[9];
    const float* Wc         = (const float*)d_in[10];
    const float* bc         = (const float*)d_in[11];
    const float* Wo         = (const float*)d_in[12];
    const float* bo         = (const float*)d_in[13];
    float* out = (float*)d_out;

    const int V_ = in_sizes[0] / D;   // 50000
    const int E_ = in_sizes[2];       // 1250000 (divisible by 16)

    float* h   = (float*)d_ws;
    float* agg = h + (size_t)V_ * D;

    hipMemsetAsync(agg, 0, (size_t)V_ * D * sizeof(float), stream);
    node_proj<<<1024, 256, 0, stream>>>(node_feats, Wn, bn, h, V_);
    edge_mfma<<<2048, 256, 0, stream>>>(edge_feats, h, src, dst,
                                        We1, be1, We2, be2, agg, E_);
    out_proj<<<1024, 256, 0, stream>>>(agg, Wc, bc, Wo, bo, out, V_);
}